// Round 3
// baseline (209.420 us; speedup 1.0000x reference)
//
#include <hip/hip_runtime.h>

typedef __attribute__((ext_vector_type(8))) short short8;
typedef __attribute__((ext_vector_type(4))) float f32x4;

#define DEV __device__ __forceinline__

constexpr int S_LEN = 2048;
constexpr int DK_LEN = 64;
constexpr int QBLK = 128;          // q rows per block (4 waves x 32)
constexpr int KBLK = 64;           // keys per KV tile
constexpr float QSCALE = 0.18033688011112042f;  // log2(e) / sqrt(64)

// LDS layout (bytes). Rows of K/V^T/P are 128B (64 bf16), 8 x 16B slots, XOR-swizzled.
constexpr int KHI = 0;             // K tile hi   [64 keys][64 dk] bf16
constexpr int KLO = 8192;          // K tile lo
constexpr int VHI = 16384;         // V^T tile hi [64 d][64 keys] bf16
constexpr int VLO = 24576;         // V^T tile lo
constexpr int PBASE = 32768;       // per-wave P: hi 4096 + lo 4096 (8192 per wave)
constexpr int LDS_BYTES = 65536;   // 64 KiB -> 2 blocks/CU

DEV unsigned int f2bf(float x) {   // fp32 -> bf16 bits, RNE
  unsigned int u = __float_as_uint(x);
  return (u + 0x7fffu + ((u >> 16) & 1u)) >> 16;
}
DEV float bf2f(unsigned int h) { return __uint_as_float(h << 16); }
// slot swizzle: spreads both d-stride-4 staging writes and row-consecutive frag reads
DEV int swz(int row, int slot) { return slot ^ ((row + (row >> 3)) & 7); }

DEV f32x4 MFMA(short8 a, short8 b, f32x4 c) {
  return __builtin_amdgcn_mfma_f32_16x16x32_bf16(a, b, c, 0, 0, 0);
}

__global__ __launch_bounds__(256, 2)
void fattn_fwd(const float* __restrict__ Qg, const float* __restrict__ Kg,
               const float* __restrict__ Vg, float* __restrict__ Og)
{
  __shared__ char smem[LDS_BYTES];
  const f32x4 vzero = {0.f, 0.f, 0.f, 0.f};
  const int tid = threadIdx.x;
  const int w  = tid >> 6;          // wave 0..3
  const int ln = tid & 63;
  const int g  = ln >> 4;           // lane group 0..3
  const int c  = ln & 15;           // lane-in-group
  const int bh = blockIdx.y;
  // causal load balance: anti-pair heavy and light q-blocks across the two
  // co-resident block slots per CU (512 blocks are all co-resident)
  const int qi = (bh < 16) ? (15 - (int)blockIdx.x) : (int)blockIdx.x;
  const int q0w = qi * QBLK + w * 32;          // this wave's first q row
  const size_t base = (size_t)bh * S_LEN * DK_LEN;
  const float* Qb = Qg + base;
  const float* Kb = Kg + base;
  const float* Vb = Vg + base;

  // ---- Q fragments in registers (scaled by log2e/sqrt(dk)), hi/lo split ----
  // B-operand layout for mfma_16x16x32: col q = c, k(dk) = 8*g + i  (contiguous 8)
  short8 qfh[2][2], qfl[2][2];     // [qtile 0..1][kstep 0..1]
#pragma unroll
  for (int qt = 0; qt < 2; ++qt) {
    const float* Qr = Qb + (size_t)(q0w + 16 * qt + c) * DK_LEN;
#pragma unroll
    for (int kk = 0; kk < 2; ++kk) {
      f32x4 a = *(const f32x4*)(Qr + kk * 32 + 8 * g);
      f32x4 b = *(const f32x4*)(Qr + kk * 32 + 8 * g + 4);
      float x[8];
#pragma unroll
      for (int i = 0; i < 4; ++i) { x[i] = a[i] * QSCALE; x[4 + i] = b[i] * QSCALE; }
#pragma unroll
      for (int i = 0; i < 8; ++i) {
        unsigned int h = f2bf(x[i]);
        unsigned int l = f2bf(x[i] - bf2f(h));
        qfh[qt][kk][i] = (short)h;
        qfl[qt][kk][i] = (short)l;
      }
    }
  }

  f32x4 acc[4][2];                  // O^T accumulator: [dtile][qtile], D: d=16*td+4g+r, q=c
#pragma unroll
  for (int td = 0; td < 4; ++td)
#pragma unroll
    for (int qt = 0; qt < 2; ++qt) acc[td][qt] = vzero;
  float m_r[2]  = {-3e38f, -3e38f};
  float lsum[2] = {0.f, 0.f};

  const int ntiles = 2 * qi + 2;    // causal: only tiles with keys <= q0+127
  for (int kt = 0; kt < ntiles; ++kt) {
    const int kv0 = kt * KBLK;
    __syncthreads();                                  // prev tile's reads done
    // ---- stage K tile: fp32 -> bf16 hi/lo, swizzled [key][dk] ----
#pragma unroll
    for (int i = 0; i < 4; ++i) {
      int f = tid + 256 * i;
      int row = f >> 4, c4 = f & 15;
      f32x4 kv = *(const f32x4*)(Kb + (size_t)(kv0 + row) * DK_LEN + c4 * 4);
      unsigned int h[4], l[4];
#pragma unroll
      for (int j = 0; j < 4; ++j) { h[j] = f2bf(kv[j]); l[j] = f2bf(kv[j] - bf2f(h[j])); }
      int byte = row * 128 + swz(row, c4 >> 1) * 16 + (c4 & 1) * 8;
      *(uint2*)(smem + KHI + byte) = make_uint2(h[0] | (h[1] << 16), h[2] | (h[3] << 16));
      *(uint2*)(smem + KLO + byte) = make_uint2(l[0] | (l[1] << 16), l[2] | (l[3] << 16));
    }
    // ---- stage V^T tile: read V row-pairs coalesced, write transposed [d][key] ----
#pragma unroll
    for (int it = 0; it < 2; ++it) {
      int p = tid + 256 * it;
      int rp = p >> 4, c4 = p & 15;                   // rp: key pair 0..31
      const float* vp = Vb + (size_t)(kv0 + 2 * rp) * DK_LEN + c4 * 4;
      f32x4 v0 = *(const f32x4*)(vp);
      f32x4 v1 = *(const f32x4*)(vp + DK_LEN);
#pragma unroll
      for (int j = 0; j < 4; ++j) {
        int d = 4 * c4 + j;
        unsigned int h0 = f2bf(v0[j]), h1 = f2bf(v1[j]);
        unsigned int l0 = f2bf(v0[j] - bf2f(h0)), l1 = f2bf(v1[j] - bf2f(h1));
        int byte = d * 128 + swz(d, rp >> 2) * 16 + (rp & 3) * 4;
        *(unsigned int*)(smem + VHI + byte) = h0 | (h1 << 16);
        *(unsigned int*)(smem + VLO + byte) = l0 | (l1 << 16);
      }
    }
    __syncthreads();                                  // tile staged

    if (kv0 > q0w + 31) continue;                     // fully masked for this wave
    const bool need_mask = (kv0 + KBLK - 1) > q0w;

    // ---- S^T = K . Q^T  (keys 64 x q 32), split: Kh*Qh + Kh*Ql + Kl*Qh ----
    f32x4 sv[2][4];                                   // [qtile][ktile16]
#pragma unroll
    for (int qt = 0; qt < 2; ++qt)
#pragma unroll
      for (int t = 0; t < 4; ++t) sv[qt][t] = vzero;
#pragma unroll
    for (int t = 0; t < 4; ++t) {
      int row = 16 * t + c;                           // A row = key (lane c)
#pragma unroll
      for (int kk = 0; kk < 2; ++kk) {
        int off = row * 128 + swz(row, 4 * kk + g) * 16;
        short8 kh = *(const short8*)(smem + KHI + off);
        short8 kl = *(const short8*)(smem + KLO + off);
#pragma unroll
        for (int qt = 0; qt < 2; ++qt) {
          sv[qt][t] = MFMA(kh, qfh[qt][kk], sv[qt][t]);
          sv[qt][t] = MFMA(kh, qfl[qt][kk], sv[qt][t]);
          sv[qt][t] = MFMA(kl, qfh[qt][kk], sv[qt][t]);
        }
      }
    }
    // causal mask (D layout: key = kv0+16t+4g+r, q = q0w+16qt+c)
    if (need_mask) {
#pragma unroll
      for (int qt = 0; qt < 2; ++qt) {
        int q = q0w + 16 * qt + c;
#pragma unroll
        for (int t = 0; t < 4; ++t)
#pragma unroll
          for (int r = 0; r < 4; ++r)
            if (kv0 + 16 * t + 4 * g + r > q) sv[qt][t][r] = -1e38f;
      }
    }

    // ---- online softmax (base-2) + P -> bf16 hi/lo -> per-wave LDS ----
    char* pw = smem + PBASE + w * 8192;
#pragma unroll
    for (int qt = 0; qt < 2; ++qt) {
      float mt = -3e38f;
#pragma unroll
      for (int t = 0; t < 4; ++t)
#pragma unroll
        for (int r = 0; r < 4; ++r) mt = fmaxf(mt, sv[qt][t][r]);
      mt = fmaxf(mt, __shfl_xor(mt, 16));
      mt = fmaxf(mt, __shfl_xor(mt, 32));
      float mn = fmaxf(m_r[qt], mt);
      float sc = exp2f(m_r[qt] - mn);
      m_r[qt] = mn;
#pragma unroll
      for (int td = 0; td < 4; ++td) acc[td][qt] *= sc;
      float ps = 0.f;
      int qrow = 16 * qt + c;
      char* ph = pw + qrow * 128;
      char* pl = ph + 4096;
#pragma unroll
      for (int t = 0; t < 4; ++t) {
        float p[4];
#pragma unroll
        for (int r = 0; r < 4; ++r) { p[r] = exp2f(sv[qt][t][r] - mn); ps += p[r]; }
        unsigned int h0 = f2bf(p[0]), h1 = f2bf(p[1]), h2 = f2bf(p[2]), h3 = f2bf(p[3]);
        unsigned int l0 = f2bf(p[0] - bf2f(h0)), l1 = f2bf(p[1] - bf2f(h1));
        unsigned int l2 = f2bf(p[2] - bf2f(h2)), l3 = f2bf(p[3] - bf2f(h3));
        int kb = 32 * t + 8 * g;                       // key-pair byte in row
        int byte = swz(qrow, kb >> 4) * 16 + (kb & 15);
        *(unsigned int*)(ph + byte)     = h0 | (h1 << 16);
        *(unsigned int*)(ph + byte + 4) = h2 | (h3 << 16);
        *(unsigned int*)(pl + byte)     = l0 | (l1 << 16);
        *(unsigned int*)(pl + byte + 4) = l2 | (l3 << 16);
      }
      lsum[qt] = lsum[qt] * sc + ps;
    }

    // ---- O^T += V^T . P^T  (wave-private P: lgkmcnt ordering, no barrier) ----
    short8 pbh[2][2], pbl[2][2];
#pragma unroll
    for (int qt = 0; qt < 2; ++qt) {
      int qrow = 16 * qt + c;
#pragma unroll
      for (int kk = 0; kk < 2; ++kk) {
        int off = qrow * 128 + swz(qrow, 4 * kk + g) * 16;
        pbh[qt][kk] = *(const short8*)(pw + off);
        pbl[qt][kk] = *(const short8*)(pw + 4096 + off);
      }
    }
#pragma unroll
    for (int td = 0; td < 4; ++td) {
      int d = 16 * td + c;                             // A row = output dim
#pragma unroll
      for (int kk = 0; kk < 2; ++kk) {
        int off = d * 128 + swz(d, 4 * kk + g) * 16;
        short8 vh = *(const short8*)(smem + VHI + off);
        short8 vl = *(const short8*)(smem + VLO + off);
#pragma unroll
        for (int qt = 0; qt < 2; ++qt) {
          acc[td][qt] = MFMA(vh, pbh[qt][kk], acc[td][qt]);
          acc[td][qt] = MFMA(vh, pbl[qt][kk], acc[td][qt]);
          acc[td][qt] = MFMA(vl, pbh[qt][kk], acc[td][qt]);
        }
      }
    }
  }

  // ---- epilogue: reduce denominator across lane groups, normalize, store ----
#pragma unroll
  for (int qt = 0; qt < 2; ++qt) {
    float l = lsum[qt];
    l += __shfl_xor(l, 16);
    l += __shfl_xor(l, 32);
    float inv = 1.f / l;
    float* Ob = Og + base + (size_t)(q0w + 16 * qt + c) * DK_LEN;
#pragma unroll
    for (int td = 0; td < 4; ++td) {
      f32x4 o = acc[td][qt] * inv;
      *(f32x4*)(Ob + 16 * td + 4 * g) = o;            // 16B stores, rows covered contiguously
    }
  }
}

extern "C" void kernel_launch(void* const* d_in, const int* in_sizes, int n_in,
                              void* d_out, int out_size, void* d_ws, size_t ws_size,
                              hipStream_t stream) {
  (void)in_sizes; (void)n_in; (void)d_ws; (void)ws_size; (void)out_size;
  const float* Q = (const float*)d_in[0];
  const float* K = (const float*)d_in[1];
  const float* V = (const float*)d_in[2];
  // d_in[3] = dk (compile-time 64), d_in[4] = causal mask (computed analytically)
  float* O = (float*)d_out;
  dim3 grid(16, 32);   // x: q-block index (remapped), y: b*h
  fattn_fwd<<<grid, dim3(256), 0, stream>>>(Q, K, V, O);
}

// Round 4
// 208.652 us; speedup vs baseline: 1.0037x; 1.0037x over previous
//
#include <hip/hip_runtime.h>

typedef __attribute__((ext_vector_type(8))) short short8;
typedef __attribute__((ext_vector_type(4))) float f32x4;

#define DEV __device__ __forceinline__

constexpr int S_LEN = 2048;
constexpr int DK_LEN = 64;
constexpr int KBLK = 64;           // keys per KV tile
constexpr float QSCALE = 0.18033688011112042f;  // log2(e) / sqrt(64)

// LDS layout (bytes). Rows of K/V^T/P are 128B (64 bf16), 8 x 16B slots, XOR-swizzled.
constexpr int KHI = 0;             // K tile hi   [64 keys][64 dk] bf16
constexpr int KLO = 8192;          // K tile lo
constexpr int VHI = 16384;         // V^T tile hi [64 d][64 keys] bf16
constexpr int VLO = 24576;         // V^T tile lo
constexpr int PBASE = 32768;       // per-wave P: hi 4096 + lo 4096 (8192 per wave)
constexpr int LDS_BYTES = 65536;   // 64 KiB -> 2 blocks/CU

DEV unsigned int f2bf(float x) {   // fp32 -> bf16 bits, RNE
  unsigned int u = __float_as_uint(x);
  return (u + 0x7fffu + ((u >> 16) & 1u)) >> 16;
}
DEV float bf2f(unsigned int h) { return __uint_as_float(h << 16); }
// slot swizzle: spreads both d-stride-4 staging writes and row-consecutive frag reads
DEV int swz(int row, int slot) { return slot ^ ((row + (row >> 3)) & 7); }

DEV f32x4 MFMA(short8 a, short8 b, f32x4 c) {
  return __builtin_amdgcn_mfma_f32_16x16x32_bf16(a, b, c, 0, 0, 0);
}

// Diagonal chunk-pairing for causal balance: 32 chunks of 64 q-rows; block j
// processes heavy chunk (31-j) as qtile0 and light chunk (j) as qtile1.
// Every wave computes exactly (hc+1)+(lc+1) = 33 tile-units -> all 512 blocks
// take equal time -> both co-resident blocks/CU stay live (8 waves/CU).
__global__ __launch_bounds__(256, 2)
void fattn_fwd(const float* __restrict__ Qg, const float* __restrict__ Kg,
               const float* __restrict__ Vg, float* __restrict__ Og)
{
  __shared__ char smem[LDS_BYTES];
  const f32x4 vzero = {0.f, 0.f, 0.f, 0.f};
  const int tid = threadIdx.x;
  const int w  = tid >> 6;          // wave 0..3
  const int ln = tid & 63;
  const int g  = ln >> 4;           // lane group 0..3
  const int c  = ln & 15;           // lane-in-group
  const int bh = blockIdx.y;
  const int j  = blockIdx.x;        // 0..15
  const int hc = 31 - j;            // heavy chunk id
  const int lc = j;                 // light chunk id
  int qb[2];                        // wave's first q row per qtile
  qb[0] = hc * 64 + 16 * w;
  qb[1] = lc * 64 + 16 * w;
  const size_t base = (size_t)bh * S_LEN * DK_LEN;
  const float* Qb = Qg + base;
  const float* Kb = Kg + base;
  const float* Vb = Vg + base;

  // ---- Q fragments in registers (scaled by log2e/sqrt(dk)), hi/lo split ----
  // B-operand layout for mfma_16x16x32: col q = c, k(dk) = 8*g + i  (contiguous 8)
  short8 qfh[2][2], qfl[2][2];     // [qtile 0..1][kstep 0..1]
#pragma unroll
  for (int qt = 0; qt < 2; ++qt) {
    const float* Qr = Qb + (size_t)(qb[qt] + c) * DK_LEN;
#pragma unroll
    for (int kk = 0; kk < 2; ++kk) {
      f32x4 a = *(const f32x4*)(Qr + kk * 32 + 8 * g);
      f32x4 b = *(const f32x4*)(Qr + kk * 32 + 8 * g + 4);
      float x[8];
#pragma unroll
      for (int i = 0; i < 4; ++i) { x[i] = a[i] * QSCALE; x[4 + i] = b[i] * QSCALE; }
#pragma unroll
      for (int i = 0; i < 8; ++i) {
        unsigned int h = f2bf(x[i]);
        unsigned int l = f2bf(x[i] - bf2f(h));
        qfh[qt][kk][i] = (short)h;
        qfl[qt][kk][i] = (short)l;
      }
    }
  }

  f32x4 acc[4][2];                  // O^T accumulator: [dtile][qtile], D: d=16*td+4g+r, q=c
#pragma unroll
  for (int td = 0; td < 4; ++td)
#pragma unroll
    for (int qt = 0; qt < 2; ++qt) acc[td][qt] = vzero;
  float m_r[2]  = {-3e38f, -3e38f};
  float lsum[2] = {0.f, 0.f};
  f32x4 sv[2][4];                   // S^T fragments [qtile][ktile16]
  char* pw = smem + PBASE + w * 8192;

  // online softmax + P->bf16 hi/lo -> per-wave LDS (wave-private, no barrier)
  auto softmax_store = [&](int qt) {
    float mt = -3e38f;
#pragma unroll
    for (int t = 0; t < 4; ++t)
#pragma unroll
      for (int r = 0; r < 4; ++r) mt = fmaxf(mt, sv[qt][t][r]);
    mt = fmaxf(mt, __shfl_xor(mt, 16));
    mt = fmaxf(mt, __shfl_xor(mt, 32));
    float mn = fmaxf(m_r[qt], mt);
    float sc = exp2f(m_r[qt] - mn);
    m_r[qt] = mn;
#pragma unroll
    for (int td = 0; td < 4; ++td) acc[td][qt] *= sc;
    float ps = 0.f;
    int qrow = 16 * qt + c;
    char* ph = pw + qrow * 128;
    char* pl = ph + 4096;
#pragma unroll
    for (int t = 0; t < 4; ++t) {
      float p[4];
#pragma unroll
      for (int r = 0; r < 4; ++r) { p[r] = exp2f(sv[qt][t][r] - mn); ps += p[r]; }
      unsigned int h0 = f2bf(p[0]), h1 = f2bf(p[1]), h2 = f2bf(p[2]), h3 = f2bf(p[3]);
      unsigned int l0 = f2bf(p[0] - bf2f(h0)), l1 = f2bf(p[1] - bf2f(h1));
      unsigned int l2 = f2bf(p[2] - bf2f(h2)), l3 = f2bf(p[3] - bf2f(h3));
      int kb = 32 * t + 8 * g;                       // key-pair byte in row
      int byte = swz(qrow, kb >> 4) * 16 + (kb & 15);
      *(unsigned int*)(ph + byte)     = h0 | (h1 << 16);
      *(unsigned int*)(ph + byte + 4) = h2 | (h3 << 16);
      *(unsigned int*)(pl + byte)     = l0 | (l1 << 16);
      *(unsigned int*)(pl + byte + 4) = l2 | (l3 << 16);
    }
    lsum[qt] = lsum[qt] * sc + ps;
  };

  const int ntiles = hc + 1;        // heavy chunk needs tiles 0..hc
  for (int kt = 0; kt < ntiles; ++kt) {
    const int kv0 = kt * KBLK;
    __syncthreads();                                  // prev tile's reads done
    // ---- stage K tile: fp32 -> bf16 hi/lo, swizzled [key][dk] ----
#pragma unroll
    for (int i = 0; i < 4; ++i) {
      int f = tid + 256 * i;
      int row = f >> 4, c4 = f & 15;
      f32x4 kv = *(const f32x4*)(Kb + (size_t)(kv0 + row) * DK_LEN + c4 * 4);
      unsigned int h[4], l[4];
#pragma unroll
      for (int jj = 0; jj < 4; ++jj) { h[jj] = f2bf(kv[jj]); l[jj] = f2bf(kv[jj] - bf2f(h[jj])); }
      int byte = row * 128 + swz(row, c4 >> 1) * 16 + (c4 & 1) * 8;
      *(uint2*)(smem + KHI + byte) = make_uint2(h[0] | (h[1] << 16), h[2] | (h[3] << 16));
      *(uint2*)(smem + KLO + byte) = make_uint2(l[0] | (l[1] << 16), l[2] | (l[3] << 16));
    }
    // ---- stage V^T tile: read V row-pairs coalesced, write transposed [d][key] ----
#pragma unroll
    for (int it = 0; it < 2; ++it) {
      int p = tid + 256 * it;
      int rp = p >> 4, c4 = p & 15;                   // rp: key pair 0..31
      const float* vp = Vb + (size_t)(kv0 + 2 * rp) * DK_LEN + c4 * 4;
      f32x4 v0 = *(const f32x4*)(vp);
      f32x4 v1 = *(const f32x4*)(vp + DK_LEN);
#pragma unroll
      for (int jj = 0; jj < 4; ++jj) {
        int d = 4 * c4 + jj;
        unsigned int h0 = f2bf(v0[jj]), h1 = f2bf(v1[jj]);
        unsigned int l0 = f2bf(v0[jj] - bf2f(h0)), l1 = f2bf(v1[jj] - bf2f(h1));
        int byte = d * 128 + swz(d, rp >> 2) * 16 + (rp & 3) * 4;
        *(unsigned int*)(smem + VHI + byte) = h0 | (h1 << 16);
        *(unsigned int*)(smem + VLO + byte) = l0 | (l1 << 16);
      }
    }
    __syncthreads();                                  // tile staged

    const bool act1 = (kv0 <= qb[1] + 15);            // light qtile still has keys
    const bool nm0  = (kv0 + KBLK - 1) > qb[0];
    const bool nm1  = (kv0 + KBLK - 1) > qb[1];

    // ---- S^T = K . Q^T  (keys 64 x q 16 per qtile), Kh*Qh + Kh*Ql + Kl*Qh ----
#pragma unroll
    for (int qt = 0; qt < 2; ++qt)
#pragma unroll
      for (int t = 0; t < 4; ++t) sv[qt][t] = vzero;
#pragma unroll
    for (int t = 0; t < 4; ++t) {
      int row = 16 * t + c;                           // A row = key (lane c)
#pragma unroll
      for (int kk = 0; kk < 2; ++kk) {
        int off = row * 128 + swz(row, 4 * kk + g) * 16;
        short8 kh = *(const short8*)(smem + KHI + off);
        short8 kl = *(const short8*)(smem + KLO + off);
        sv[0][t] = MFMA(kh, qfh[0][kk], sv[0][t]);
        sv[0][t] = MFMA(kh, qfl[0][kk], sv[0][t]);
        sv[0][t] = MFMA(kl, qfh[0][kk], sv[0][t]);
        if (act1) {
          sv[1][t] = MFMA(kh, qfh[1][kk], sv[1][t]);
          sv[1][t] = MFMA(kh, qfl[1][kk], sv[1][t]);
          sv[1][t] = MFMA(kl, qfh[1][kk], sv[1][t]);
        }
      }
    }
    // causal mask (D layout: key = kv0+16t+4g+r, q = qb[qt]+c)
    if (nm0) {
      int q = qb[0] + c;
#pragma unroll
      for (int t = 0; t < 4; ++t)
#pragma unroll
        for (int r = 0; r < 4; ++r)
          if (kv0 + 16 * t + 4 * g + r > q) sv[0][t][r] = -1e38f;
    }
    if (act1 && nm1) {
      int q = qb[1] + c;
#pragma unroll
      for (int t = 0; t < 4; ++t)
#pragma unroll
        for (int r = 0; r < 4; ++r)
          if (kv0 + 16 * t + 4 * g + r > q) sv[1][t][r] = -1e38f;
    }

    softmax_store(0);
    if (act1) softmax_store(1);

    // ---- O^T += V^T . P^T  (wave-private P: lgkmcnt ordering, no barrier) ----
    short8 pbh[2][2], pbl[2][2];
#pragma unroll
    for (int kk = 0; kk < 2; ++kk) {
      int qrow = c;
      int off = qrow * 128 + swz(qrow, 4 * kk + g) * 16;
      pbh[0][kk] = *(const short8*)(pw + off);
      pbl[0][kk] = *(const short8*)(pw + 4096 + off);
    }
    if (act1) {
#pragma unroll
      for (int kk = 0; kk < 2; ++kk) {
        int qrow = 16 + c;
        int off = qrow * 128 + swz(qrow, 4 * kk + g) * 16;
        pbh[1][kk] = *(const short8*)(pw + off);
        pbl[1][kk] = *(const short8*)(pw + 4096 + off);
      }
    }
#pragma unroll
    for (int td = 0; td < 4; ++td) {
      int d = 16 * td + c;                             // A row = output dim
#pragma unroll
      for (int kk = 0; kk < 2; ++kk) {
        int off = d * 128 + swz(d, 4 * kk + g) * 16;
        short8 vh = *(const short8*)(smem + VHI + off);
        short8 vl = *(const short8*)(smem + VLO + off);
        acc[td][0] = MFMA(vh, pbh[0][kk], acc[td][0]);
        acc[td][0] = MFMA(vh, pbl[0][kk], acc[td][0]);
        acc[td][0] = MFMA(vl, pbh[0][kk], acc[td][0]);
        if (act1) {
          acc[td][1] = MFMA(vh, pbh[1][kk], acc[td][1]);
          acc[td][1] = MFMA(vh, pbl[1][kk], acc[td][1]);
          acc[td][1] = MFMA(vl, pbh[1][kk], acc[td][1]);
        }
      }
    }
  }

  // ---- epilogue: reduce denominator across lane groups, normalize, store ----
#pragma unroll
  for (int qt = 0; qt < 2; ++qt) {
    float l = lsum[qt];
    l += __shfl_xor(l, 16);
    l += __shfl_xor(l, 32);
    float inv = 1.f / l;
    float* Ob = Og + base + (size_t)(qb[qt] + c) * DK_LEN;
#pragma unroll
    for (int td = 0; td < 4; ++td) {
      f32x4 o = acc[td][qt] * inv;
      *(f32x4*)(Ob + 16 * td + 4 * g) = o;            // 16B stores, rows covered contiguously
    }
  }
}

extern "C" void kernel_launch(void* const* d_in, const int* in_sizes, int n_in,
                              void* d_out, int out_size, void* d_ws, size_t ws_size,
                              hipStream_t stream) {
  (void)in_sizes; (void)n_in; (void)d_ws; (void)ws_size; (void)out_size;
  const float* Q = (const float*)d_in[0];
  const float* K = (const float*)d_in[1];
  const float* V = (const float*)d_in[2];
  // d_in[3] = dk (compile-time 64), d_in[4] = causal mask (computed analytically)
  float* O = (float*)d_out;
  dim3 grid(16, 32);   // x: chunk-pair index j, y: b*h
  fattn_fwd<<<grid, dim3(256), 0, stream>>>(Q, K, V, O);
}

// Round 5
// 204.484 us; speedup vs baseline: 1.0241x; 1.0204x over previous
//
#include <hip/hip_runtime.h>

typedef __attribute__((ext_vector_type(8))) short short8;
typedef __attribute__((ext_vector_type(4))) float f32x4;

#define DEV __device__ __forceinline__

constexpr int S_LEN = 2048;
constexpr int DK_LEN = 64;
constexpr int KBLK = 64;           // keys per KV tile
constexpr float QSCALE = 0.18033688011112042f;  // log2(e) / sqrt(64)

// Tile image layout (bytes) — identical in ws and LDS. Rows are 128B (64 bf16),
// 8 x 16B slots, XOR-swizzled.
constexpr int KHI = 0;             // K tile hi   [64 keys][64 dk] bf16
constexpr int KLO = 8192;          // K tile lo
constexpr int VHI = 16384;         // V^T tile hi [64 d][64 keys] bf16
constexpr int VLO = 24576;         // V^T tile lo
constexpr int TILE_IMG = 32768;    // bytes per (bh, kt) tile image in ws
constexpr int PBASE = 32768;       // LDS: per-wave P, hi 4096 + lo 4096 (8192/wave)
constexpr int LDS_BYTES = 65536;   // 64 KiB -> 2 blocks/CU

DEV unsigned int f2bf(float x) {   // fp32 -> bf16 bits, RNE
  unsigned int u = __float_as_uint(x);
  return (u + 0x7fffu + ((u >> 16) & 1u)) >> 16;
}
DEV float bf2f(unsigned int h) { return __uint_as_float(h << 16); }
// slot swizzle: spreads both d-stride-4 staging writes and row-consecutive frag reads
DEV int swz(int row, int slot) { return slot ^ ((row + (row >> 3)) & 7); }

DEV f32x4 MFMA(short8 a, short8 b, f32x4 c) {
  return __builtin_amdgcn_mfma_f32_16x16x32_bf16(a, b, c, 0, 0, 0);
}

DEV void gload_lds16(const void* g, void* l) {  // 16B async global->LDS
  __builtin_amdgcn_global_load_lds(
      (const __attribute__((address_space(1))) unsigned int*)g,
      (__attribute__((address_space(3))) unsigned int*)l, 16, 0, 0);
}

// ---------------- preprocess: K/V fp32 -> bf16 hi/lo swizzled tile images ----
__global__ __launch_bounds__(256)
void prep_kv(const float* __restrict__ Kg, const float* __restrict__ Vg,
             char* __restrict__ ws)
{
  const int tid = threadIdx.x;
  const int kt  = blockIdx.x;
  const int bh  = blockIdx.y;
  const int kv0 = kt * KBLK;
  const size_t base = (size_t)bh * S_LEN * DK_LEN;
  const float* Kb = Kg + base;
  const float* Vb = Vg + base;
  char* wt = ws + ((size_t)bh * 32 + kt) * TILE_IMG;

#pragma unroll
  for (int i = 0; i < 4; ++i) {            // K tile: [key][dk]
    int f = tid + 256 * i;
    int row = f >> 4, c4 = f & 15;
    f32x4 kv = *(const f32x4*)(Kb + (size_t)(kv0 + row) * DK_LEN + c4 * 4);
    unsigned int h[4], l[4];
#pragma unroll
    for (int j = 0; j < 4; ++j) { h[j] = f2bf(kv[j]); l[j] = f2bf(kv[j] - bf2f(h[j])); }
    int byte = row * 128 + swz(row, c4 >> 1) * 16 + (c4 & 1) * 8;
    *(uint2*)(wt + KHI + byte) = make_uint2(h[0] | (h[1] << 16), h[2] | (h[3] << 16));
    *(uint2*)(wt + KLO + byte) = make_uint2(l[0] | (l[1] << 16), l[2] | (l[3] << 16));
  }
#pragma unroll
  for (int it = 0; it < 2; ++it) {         // V^T tile: [d][key]
    int p = tid + 256 * it;
    int rp = p >> 4, c4 = p & 15;          // rp: key pair 0..31
    const float* vp = Vb + (size_t)(kv0 + 2 * rp) * DK_LEN + c4 * 4;
    f32x4 v0 = *(const f32x4*)(vp);
    f32x4 v1 = *(const f32x4*)(vp + DK_LEN);
#pragma unroll
    for (int j = 0; j < 4; ++j) {
      int d = 4 * c4 + j;
      unsigned int h0 = f2bf(v0[j]), h1 = f2bf(v1[j]);
      unsigned int l0 = f2bf(v0[j] - bf2f(h0)), l1 = f2bf(v1[j] - bf2f(h1));
      int byte = d * 128 + swz(d, rp >> 2) * 16 + (rp & 3) * 4;
      *(unsigned int*)(wt + VHI + byte) = h0 | (h1 << 16);
      *(unsigned int*)(wt + VLO + byte) = l0 | (l1 << 16);
    }
  }
}

// ---------------- main: diagonal chunk-paired causal flash attention ----------
// 32 chunks of 64 q-rows; block j processes heavy chunk (31-j) as qtile0 and
// light chunk (j) as qtile1 -> every wave = 33 tile-units -> balanced blocks.
template<bool PRE>
__global__ __launch_bounds__(256, 2)
void fattn_fwd(const float* __restrict__ Qg, const float* __restrict__ Kg,
               const float* __restrict__ Vg, float* __restrict__ Og,
               const char* __restrict__ ws)
{
  __shared__ char smem[LDS_BYTES];
  const f32x4 vzero = {0.f, 0.f, 0.f, 0.f};
  const int tid = threadIdx.x;
  const int w  = tid >> 6;          // wave 0..3
  const int ln = tid & 63;
  const int g  = ln >> 4;           // lane group 0..3
  const int c  = ln & 15;           // lane-in-group
  const int bh = blockIdx.y;
  const int j  = blockIdx.x;        // 0..15
  const int hc = 31 - j;            // heavy chunk id
  const int lc = j;                 // light chunk id
  int qb[2];
  qb[0] = hc * 64 + 16 * w;
  qb[1] = lc * 64 + 16 * w;
  const size_t base = (size_t)bh * S_LEN * DK_LEN;
  const float* Qb = Qg + base;
  const float* Kb = Kg + base;
  const float* Vb = Vg + base;
  const char* wsb = ws + (size_t)bh * 32 * TILE_IMG;

  // ---- Q fragments in registers (scaled), hi/lo split ----
  short8 qfh[2][2], qfl[2][2];     // [qtile][kstep]
#pragma unroll
  for (int qt = 0; qt < 2; ++qt) {
    const float* Qr = Qb + (size_t)(qb[qt] + c) * DK_LEN;
#pragma unroll
    for (int kk = 0; kk < 2; ++kk) {
      f32x4 a = *(const f32x4*)(Qr + kk * 32 + 8 * g);
      f32x4 b = *(const f32x4*)(Qr + kk * 32 + 8 * g + 4);
      float x[8];
#pragma unroll
      for (int i = 0; i < 4; ++i) { x[i] = a[i] * QSCALE; x[4 + i] = b[i] * QSCALE; }
#pragma unroll
      for (int i = 0; i < 8; ++i) {
        unsigned int h = f2bf(x[i]);
        unsigned int l = f2bf(x[i] - bf2f(h));
        qfh[qt][kk][i] = (short)h;
        qfl[qt][kk][i] = (short)l;
      }
    }
  }

  f32x4 acc[4][2];                  // O^T acc: [dtile][qtile]; D: d=16td+4g+r, q=c
#pragma unroll
  for (int td = 0; td < 4; ++td)
#pragma unroll
    for (int qt = 0; qt < 2; ++qt) acc[td][qt] = vzero;
  float m_r[2]  = {-3e38f, -3e38f};
  float lsum[2] = {0.f, 0.f};
  f32x4 sv[2][4];                   // S^T fragments [qtile][ktile16]
  char* pw = smem + PBASE + w * 8192;

  auto softmax_store = [&](int qt) {
    float mt = -3e38f;
#pragma unroll
    for (int t = 0; t < 4; ++t)
#pragma unroll
      for (int r = 0; r < 4; ++r) mt = fmaxf(mt, sv[qt][t][r]);
    mt = fmaxf(mt, __shfl_xor(mt, 16));
    mt = fmaxf(mt, __shfl_xor(mt, 32));
    float mn = fmaxf(m_r[qt], mt);
    float sc = exp2f(m_r[qt] - mn);
    m_r[qt] = mn;
#pragma unroll
    for (int td = 0; td < 4; ++td) acc[td][qt] *= sc;
    float ps = 0.f;
    int qrow = 16 * qt + c;
    char* ph = pw + qrow * 128;
    char* pl = ph + 4096;
#pragma unroll
    for (int t = 0; t < 4; ++t) {
      float p[4];
#pragma unroll
      for (int r = 0; r < 4; ++r) { p[r] = exp2f(sv[qt][t][r] - mn); ps += p[r]; }
      unsigned int h0 = f2bf(p[0]), h1 = f2bf(p[1]), h2 = f2bf(p[2]), h3 = f2bf(p[3]);
      unsigned int l0 = f2bf(p[0] - bf2f(h0)), l1 = f2bf(p[1] - bf2f(h1));
      unsigned int l2 = f2bf(p[2] - bf2f(h2)), l3 = f2bf(p[3] - bf2f(h3));
      int kb = 32 * t + 8 * g;
      int byte = swz(qrow, kb >> 4) * 16 + (kb & 15);
      *(unsigned int*)(ph + byte)     = h0 | (h1 << 16);
      *(unsigned int*)(ph + byte + 4) = h2 | (h3 << 16);
      *(unsigned int*)(pl + byte)     = l0 | (l1 << 16);
      *(unsigned int*)(pl + byte + 4) = l2 | (l3 << 16);
    }
    lsum[qt] = lsum[qt] * sc + ps;
  };

  const int ntiles = hc + 1;
  for (int kt = 0; kt < ntiles; ++kt) {
    const int kv0 = kt * KBLK;
    __syncthreads();                                  // prev tile's reads done
    if constexpr (PRE) {
      // pure DMA staging: 32KB pre-swizzled tile image -> LDS (linear dest)
      const char* wt = wsb + (size_t)kt * TILE_IMG;
#pragma unroll
      for (int i = 0; i < 8; ++i)
        gload_lds16(wt + i * 4096 + tid * 16, smem + i * 4096 + w * 1024);
    } else {
      // in-kernel conversion staging (ws too small fallback)
#pragma unroll
      for (int i = 0; i < 4; ++i) {
        int f = tid + 256 * i;
        int row = f >> 4, c4 = f & 15;
        f32x4 kv = *(const f32x4*)(Kb + (size_t)(kv0 + row) * DK_LEN + c4 * 4);
        unsigned int h[4], l[4];
#pragma unroll
        for (int jj = 0; jj < 4; ++jj) { h[jj] = f2bf(kv[jj]); l[jj] = f2bf(kv[jj] - bf2f(h[jj])); }
        int byte = row * 128 + swz(row, c4 >> 1) * 16 + (c4 & 1) * 8;
        *(uint2*)(smem + KHI + byte) = make_uint2(h[0] | (h[1] << 16), h[2] | (h[3] << 16));
        *(uint2*)(smem + KLO + byte) = make_uint2(l[0] | (l[1] << 16), l[2] | (l[3] << 16));
      }
#pragma unroll
      for (int it = 0; it < 2; ++it) {
        int p = tid + 256 * it;
        int rp = p >> 4, c4 = p & 15;
        const float* vp = Vb + (size_t)(kv0 + 2 * rp) * DK_LEN + c4 * 4;
        f32x4 v0 = *(const f32x4*)(vp);
        f32x4 v1 = *(const f32x4*)(vp + DK_LEN);
#pragma unroll
        for (int jj = 0; jj < 4; ++jj) {
          int d = 4 * c4 + jj;
          unsigned int h0 = f2bf(v0[jj]), h1 = f2bf(v1[jj]);
          unsigned int l0 = f2bf(v0[jj] - bf2f(h0)), l1 = f2bf(v1[jj] - bf2f(h1));
          int byte = d * 128 + swz(d, rp >> 2) * 16 + (rp & 3) * 4;
          *(unsigned int*)(smem + VHI + byte) = h0 | (h1 << 16);
          *(unsigned int*)(smem + VLO + byte) = l0 | (l1 << 16);
        }
      }
    }
    __syncthreads();                                  // tile staged (drains vmcnt)

    const bool act1 = (kv0 <= qb[1] + 15);            // light qtile still has keys
    const bool nm0  = (kv0 + KBLK - 1) > qb[0];
    const bool nm1  = (kv0 + KBLK - 1) > qb[1];

    // ---- S^T = K . Q^T: Kh*Qh + Kh*Ql + Kl*Qh ----
#pragma unroll
    for (int qt = 0; qt < 2; ++qt)
#pragma unroll
      for (int t = 0; t < 4; ++t) sv[qt][t] = vzero;
#pragma unroll
    for (int t = 0; t < 4; ++t) {
      int row = 16 * t + c;                           // A row = key
#pragma unroll
      for (int kk = 0; kk < 2; ++kk) {
        int off = row * 128 + swz(row, 4 * kk + g) * 16;
        short8 kh = *(const short8*)(smem + KHI + off);
        short8 kl = *(const short8*)(smem + KLO + off);
        sv[0][t] = MFMA(kh, qfh[0][kk], sv[0][t]);
        sv[0][t] = MFMA(kh, qfl[0][kk], sv[0][t]);
        sv[0][t] = MFMA(kl, qfh[0][kk], sv[0][t]);
        if (act1) {
          sv[1][t] = MFMA(kh, qfh[1][kk], sv[1][t]);
          sv[1][t] = MFMA(kh, qfl[1][kk], sv[1][t]);
          sv[1][t] = MFMA(kl, qfh[1][kk], sv[1][t]);
        }
      }
    }
    // causal mask (D layout: key = kv0+16t+4g+r, q = qb[qt]+c)
    if (nm0) {
      int q = qb[0] + c;
#pragma unroll
      for (int t = 0; t < 4; ++t)
#pragma unroll
        for (int r = 0; r < 4; ++r)
          if (kv0 + 16 * t + 4 * g + r > q) sv[0][t][r] = -1e38f;
    }
    if (act1 && nm1) {
      int q = qb[1] + c;
#pragma unroll
      for (int t = 0; t < 4; ++t)
#pragma unroll
        for (int r = 0; r < 4; ++r)
          if (kv0 + 16 * t + 4 * g + r > q) sv[1][t][r] = -1e38f;
    }

    softmax_store(0);
    if (act1) softmax_store(1);

    // ---- O^T += V^T . P^T (wave-private P, lgkmcnt ordering) ----
    short8 pbh[2][2], pbl[2][2];
#pragma unroll
    for (int kk = 0; kk < 2; ++kk) {
      int off = c * 128 + swz(c, 4 * kk + g) * 16;
      pbh[0][kk] = *(const short8*)(pw + off);
      pbl[0][kk] = *(const short8*)(pw + 4096 + off);
    }
    if (act1) {
#pragma unroll
      for (int kk = 0; kk < 2; ++kk) {
        int qrow = 16 + c;
        int off = qrow * 128 + swz(qrow, 4 * kk + g) * 16;
        pbh[1][kk] = *(const short8*)(pw + off);
        pbl[1][kk] = *(const short8*)(pw + 4096 + off);
      }
    }
#pragma unroll
    for (int td = 0; td < 4; ++td) {
      int d = 16 * td + c;                             // A row = output dim
#pragma unroll
      for (int kk = 0; kk < 2; ++kk) {
        int off = d * 128 + swz(d, 4 * kk + g) * 16;
        short8 vh = *(const short8*)(smem + VHI + off);
        short8 vl = *(const short8*)(smem + VLO + off);
        acc[td][0] = MFMA(vh, pbh[0][kk], acc[td][0]);
        acc[td][0] = MFMA(vh, pbl[0][kk], acc[td][0]);
        acc[td][0] = MFMA(vl, pbh[0][kk], acc[td][0]);
        if (act1) {
          acc[td][1] = MFMA(vh, pbh[1][kk], acc[td][1]);
          acc[td][1] = MFMA(vh, pbl[1][kk], acc[td][1]);
          acc[td][1] = MFMA(vl, pbh[1][kk], acc[td][1]);
        }
      }
    }
  }

  // ---- epilogue ----
#pragma unroll
  for (int qt = 0; qt < 2; ++qt) {
    float l = lsum[qt];
    l += __shfl_xor(l, 16);
    l += __shfl_xor(l, 32);
    float inv = 1.f / l;
    float* Ob = Og + base + (size_t)(qb[qt] + c) * DK_LEN;
#pragma unroll
    for (int td = 0; td < 4; ++td) {
      f32x4 o = acc[td][qt] * inv;
      *(f32x4*)(Ob + 16 * td + 4 * g) = o;
    }
  }
}

extern "C" void kernel_launch(void* const* d_in, const int* in_sizes, int n_in,
                              void* d_out, int out_size, void* d_ws, size_t ws_size,
                              hipStream_t stream) {
  (void)in_sizes; (void)n_in; (void)out_size;
  const float* Q = (const float*)d_in[0];
  const float* K = (const float*)d_in[1];
  const float* V = (const float*)d_in[2];
  float* O = (float*)d_out;
  dim3 grid(16, 32);   // x: chunk-pair index j, y: b*h
  const size_t WS_NEED = (size_t)32 * 32 * TILE_IMG;  // 32 MB
  if (ws_size >= WS_NEED) {
    prep_kv<<<dim3(32, 32), 256, 0, stream>>>(K, V, (char*)d_ws);
    fattn_fwd<true><<<grid, dim3(256), 0, stream>>>(Q, K, V, O, (const char*)d_ws);
  } else {
    fattn_fwd<false><<<grid, dim3(256), 0, stream>>>(Q, K, V, O, (const char*)d_ws);
  }
}

// Round 6
// 197.771 us; speedup vs baseline: 1.0589x; 1.0339x over previous
//
#include <hip/hip_runtime.h>

typedef __attribute__((ext_vector_type(8))) short short8;
typedef __attribute__((ext_vector_type(4))) float f32x4;
typedef __attribute__((ext_vector_type(4))) unsigned int u32x4;

#define DEV __device__ __forceinline__

constexpr int S_LEN = 2048;
constexpr int DK_LEN = 64;
constexpr int KBLK = 64;           // keys per KV tile
constexpr float QSCALE = 0.18033688011112042f;  // log2(e) / sqrt(64)

// Tile image layout (bytes) — identical in ws and LDS. Rows are 128B (64 bf16),
// 8 x 16B slots, XOR-swizzled.
constexpr int KHI = 0;             // K tile hi   [64 keys][64 dk] bf16
constexpr int KLO = 8192;          // K tile lo
constexpr int VHI = 16384;         // V^T tile hi [64 d][64 keys] bf16
constexpr int VLO = 24576;         // V^T tile lo
constexpr int TILE_IMG = 32768;    // bytes per (bh, kt) tile image in ws
constexpr int PBASE = 32768;       // LDS: per-wave P, hi 4096 + lo 4096 (8192/wave)
constexpr int LDS_BYTES = 65536;   // 64 KiB -> 2 blocks/CU

// HW packed converter: D.lo16 = bf16(a), D.hi16 = bf16(b). 1 instr per 2 values
// (vs ~5 VALU ops/value for manual RNE bit-math — this was ~70% of softmax VALU).
DEV unsigned int cvtpk(float a, float b) {
  unsigned int r;
  asm("v_cvt_pk_bf16_f32 %0, %1, %2" : "=v"(r) : "v"(a), "v"(b));
  return r;
}
DEV float lo16f(unsigned int w) { return __uint_as_float(w << 16); }
DEV float hi16f(unsigned int w) { return __uint_as_float(w & 0xffff0000u); }
DEV short8 asS8(u32x4 v) { return __builtin_bit_cast(short8, v); }

// slot swizzle: spreads both d-stride-4 staging writes and row-consecutive frag reads
DEV int swz(int row, int slot) { return slot ^ ((row + (row >> 3)) & 7); }

DEV f32x4 MFMA(short8 a, short8 b, f32x4 c) {
  return __builtin_amdgcn_mfma_f32_16x16x32_bf16(a, b, c, 0, 0, 0);
}

DEV void gload_lds16(const void* g, void* l) {  // 16B async global->LDS
  __builtin_amdgcn_global_load_lds(
      (const __attribute__((address_space(1))) unsigned int*)g,
      (__attribute__((address_space(3))) unsigned int*)l, 16, 0, 0);
}

// ---------------- preprocess: K/V fp32 -> bf16 hi/lo swizzled tile images ----
__global__ __launch_bounds__(256)
void prep_kv(const float* __restrict__ Kg, const float* __restrict__ Vg,
             char* __restrict__ ws)
{
  const int tid = threadIdx.x;
  const int kt  = blockIdx.x;
  const int bh  = blockIdx.y;
  const int kv0 = kt * KBLK;
  const size_t base = (size_t)bh * S_LEN * DK_LEN;
  const float* Kb = Kg + base;
  const float* Vb = Vg + base;
  char* wt = ws + ((size_t)bh * 32 + kt) * TILE_IMG;

#pragma unroll
  for (int i = 0; i < 4; ++i) {            // K tile: [key][dk]
    int f = tid + 256 * i;
    int row = f >> 4, c4 = f & 15;
    f32x4 kv = *(const f32x4*)(Kb + (size_t)(kv0 + row) * DK_LEN + c4 * 4);
    unsigned int h01 = cvtpk(kv[0], kv[1]), h23 = cvtpk(kv[2], kv[3]);
    float l0 = kv[0] - lo16f(h01), l1 = kv[1] - hi16f(h01);
    float l2 = kv[2] - lo16f(h23), l3 = kv[3] - hi16f(h23);
    int byte = row * 128 + swz(row, c4 >> 1) * 16 + (c4 & 1) * 8;
    *(uint2*)(wt + KHI + byte) = make_uint2(h01, h23);
    *(uint2*)(wt + KLO + byte) = make_uint2(cvtpk(l0, l1), cvtpk(l2, l3));
  }
#pragma unroll
  for (int it = 0; it < 2; ++it) {         // V^T tile: [d][key]
    int p = tid + 256 * it;
    int rp = p >> 4, c4 = p & 15;          // rp: key pair 0..31
    const float* vp = Vb + (size_t)(kv0 + 2 * rp) * DK_LEN + c4 * 4;
    f32x4 v0 = *(const f32x4*)(vp);
    f32x4 v1 = *(const f32x4*)(vp + DK_LEN);
#pragma unroll
    for (int j = 0; j < 4; ++j) {
      int d = 4 * c4 + j;
      unsigned int h = cvtpk(v0[j], v1[j]);
      float l0 = v0[j] - lo16f(h), l1 = v1[j] - hi16f(h);
      int byte = d * 128 + swz(d, rp >> 2) * 16 + (rp & 3) * 4;
      *(unsigned int*)(wt + VHI + byte) = h;
      *(unsigned int*)(wt + VLO + byte) = cvtpk(l0, l1);
    }
  }
}

// ---------------- main: diagonal chunk-paired causal flash attention ----------
// 32 chunks of 64 q-rows; block j processes heavy chunk (31-j) as qtile0 and
// light chunk (j) as qtile1 -> every wave = 33 tile-units -> balanced blocks.
template<bool PRE>
__global__ __launch_bounds__(256, 2)
void fattn_fwd(const float* __restrict__ Qg, const float* __restrict__ Kg,
               const float* __restrict__ Vg, float* __restrict__ Og,
               const char* __restrict__ ws)
{
  __shared__ char smem[LDS_BYTES];
  const f32x4 vzero = {0.f, 0.f, 0.f, 0.f};
  const int tid = threadIdx.x;
  const int w  = tid >> 6;          // wave 0..3
  const int ln = tid & 63;
  const int g  = ln >> 4;           // lane group 0..3
  const int c  = ln & 15;           // lane-in-group
  const int bh = blockIdx.y;
  const int j  = blockIdx.x;        // 0..15
  const int hc = 31 - j;            // heavy chunk id
  const int lc = j;                 // light chunk id
  int qb[2];
  qb[0] = hc * 64 + 16 * w;
  qb[1] = lc * 64 + 16 * w;
  const size_t base = (size_t)bh * S_LEN * DK_LEN;
  const float* Qb = Qg + base;
  const float* Kb = Kg + base;
  const float* Vb = Vg + base;
  const char* wsb = ws + (size_t)bh * 32 * TILE_IMG;

  // ---- Q fragments in registers (scaled), hi/lo split via cvt_pk ----
  short8 qfh[2][2], qfl[2][2];     // [qtile][kstep]
#pragma unroll
  for (int qt = 0; qt < 2; ++qt) {
    const float* Qr = Qb + (size_t)(qb[qt] + c) * DK_LEN;
#pragma unroll
    for (int kk = 0; kk < 2; ++kk) {
      f32x4 a = *(const f32x4*)(Qr + kk * 32 + 8 * g);
      f32x4 b = *(const f32x4*)(Qr + kk * 32 + 8 * g + 4);
      float x[8];
#pragma unroll
      for (int i = 0; i < 4; ++i) { x[i] = a[i] * QSCALE; x[4 + i] = b[i] * QSCALE; }
      u32x4 H, L;
#pragma unroll
      for (int i = 0; i < 4; ++i) {
        H[i] = cvtpk(x[2 * i], x[2 * i + 1]);
        float l0 = x[2 * i] - lo16f(H[i]);
        float l1 = x[2 * i + 1] - hi16f(H[i]);
        L[i] = cvtpk(l0, l1);
      }
      qfh[qt][kk] = asS8(H);
      qfl[qt][kk] = asS8(L);
    }
  }

  f32x4 acc[4][2];                  // O^T acc: [dtile][qtile]; D: d=16td+4g+r, q=c
#pragma unroll
  for (int td = 0; td < 4; ++td)
#pragma unroll
    for (int qt = 0; qt < 2; ++qt) acc[td][qt] = vzero;
  float m_r[2]  = {-3e38f, -3e38f};
  float lsum[2] = {0.f, 0.f};
  f32x4 sv[2][4];                   // S^T fragments [qtile][ktile16]
  char* pw = smem + PBASE + w * 8192;

  auto softmax_store = [&](int qt) {
    // max-reduce as an explicit tree (fp max chains don't reassociate at -O3)
    float tm[4];
#pragma unroll
    for (int t = 0; t < 4; ++t)
      tm[t] = fmaxf(fmaxf(sv[qt][t][0], sv[qt][t][1]),
                    fmaxf(sv[qt][t][2], sv[qt][t][3]));
    float mt = fmaxf(fmaxf(tm[0], tm[1]), fmaxf(tm[2], tm[3]));
    mt = fmaxf(mt, __shfl_xor(mt, 16));
    mt = fmaxf(mt, __shfl_xor(mt, 32));
    float mn = fmaxf(m_r[qt], mt);
    float sc = exp2f(m_r[qt] - mn);
    m_r[qt] = mn;
#pragma unroll
    for (int td = 0; td < 4; ++td) acc[td][qt] *= sc;
    int qrow = 16 * qt + c;
    char* ph = pw + qrow * 128;
    char* pl = ph + 4096;
    float tsum[4];
#pragma unroll
    for (int t = 0; t < 4; ++t) {
      float p0 = exp2f(sv[qt][t][0] - mn), p1 = exp2f(sv[qt][t][1] - mn);
      float p2 = exp2f(sv[qt][t][2] - mn), p3 = exp2f(sv[qt][t][3] - mn);
      tsum[t] = (p0 + p1) + (p2 + p3);
      unsigned int w01 = cvtpk(p0, p1), w23 = cvtpk(p2, p3);
      float l0 = p0 - lo16f(w01), l1 = p1 - hi16f(w01);
      float l2 = p2 - lo16f(w23), l3 = p3 - hi16f(w23);
      int kb = 32 * t + 8 * g;
      int byte = swz(qrow, kb >> 4) * 16 + (kb & 15);
      *(unsigned int*)(ph + byte)     = w01;
      *(unsigned int*)(ph + byte + 4) = w23;
      *(unsigned int*)(pl + byte)     = cvtpk(l0, l1);
      *(unsigned int*)(pl + byte + 4) = cvtpk(l2, l3);
    }
    lsum[qt] = lsum[qt] * sc + ((tsum[0] + tsum[1]) + (tsum[2] + tsum[3]));
  };

  const int ntiles = hc + 1;
  for (int kt = 0; kt < ntiles; ++kt) {
    const int kv0 = kt * KBLK;
    __syncthreads();                                  // prev tile's reads done
    if constexpr (PRE) {
      // pure DMA staging: 32KB pre-swizzled tile image -> LDS (linear dest)
      const char* wt = wsb + (size_t)kt * TILE_IMG;
#pragma unroll
      for (int i = 0; i < 8; ++i)
        gload_lds16(wt + i * 4096 + tid * 16, smem + i * 4096 + w * 1024);
    } else {
      // in-kernel conversion staging (ws too small fallback)
#pragma unroll
      for (int i = 0; i < 4; ++i) {
        int f = tid + 256 * i;
        int row = f >> 4, c4 = f & 15;
        f32x4 kv = *(const f32x4*)(Kb + (size_t)(kv0 + row) * DK_LEN + c4 * 4);
        unsigned int h01 = cvtpk(kv[0], kv[1]), h23 = cvtpk(kv[2], kv[3]);
        float l0 = kv[0] - lo16f(h01), l1 = kv[1] - hi16f(h01);
        float l2 = kv[2] - lo16f(h23), l3 = kv[3] - hi16f(h23);
        int byte = row * 128 + swz(row, c4 >> 1) * 16 + (c4 & 1) * 8;
        *(uint2*)(smem + KHI + byte) = make_uint2(h01, h23);
        *(uint2*)(smem + KLO + byte) = make_uint2(cvtpk(l0, l1), cvtpk(l2, l3));
      }
#pragma unroll
      for (int it = 0; it < 2; ++it) {
        int p = tid + 256 * it;
        int rp = p >> 4, c4 = p & 15;
        const float* vp = Vb + (size_t)(kv0 + 2 * rp) * DK_LEN + c4 * 4;
        f32x4 v0 = *(const f32x4*)(vp);
        f32x4 v1 = *(const f32x4*)(vp + DK_LEN);
#pragma unroll
        for (int jj = 0; jj < 4; ++jj) {
          int d = 4 * c4 + jj;
          unsigned int h = cvtpk(v0[jj], v1[jj]);
          float l0 = v0[jj] - lo16f(h), l1 = v1[jj] - hi16f(h);
          int byte = d * 128 + swz(d, rp >> 2) * 16 + (rp & 3) * 4;
          *(unsigned int*)(smem + VHI + byte) = h;
          *(unsigned int*)(smem + VLO + byte) = cvtpk(l0, l1);
        }
      }
    }
    __syncthreads();                                  // tile staged (drains vmcnt)

    const bool act1 = (kv0 <= qb[1] + 15);            // light qtile still has keys
    const bool nm0  = (kv0 + KBLK - 1) > qb[0];
    const bool nm1  = (kv0 + KBLK - 1) > qb[1];

    // ---- S^T = K . Q^T: Kh*Qh + Kh*Ql + Kl*Qh ----
#pragma unroll
    for (int qt = 0; qt < 2; ++qt)
#pragma unroll
      for (int t = 0; t < 4; ++t) sv[qt][t] = vzero;
#pragma unroll
    for (int t = 0; t < 4; ++t) {
      int row = 16 * t + c;                           // A row = key
#pragma unroll
      for (int kk = 0; kk < 2; ++kk) {
        int off = row * 128 + swz(row, 4 * kk + g) * 16;
        short8 kh = *(const short8*)(smem + KHI + off);
        short8 kl = *(const short8*)(smem + KLO + off);
        sv[0][t] = MFMA(kh, qfh[0][kk], sv[0][t]);
        sv[0][t] = MFMA(kh, qfl[0][kk], sv[0][t]);
        sv[0][t] = MFMA(kl, qfh[0][kk], sv[0][t]);
        if (act1) {
          sv[1][t] = MFMA(kh, qfh[1][kk], sv[1][t]);
          sv[1][t] = MFMA(kh, qfl[1][kk], sv[1][t]);
          sv[1][t] = MFMA(kl, qfh[1][kk], sv[1][t]);
        }
      }
    }
    // causal mask (D layout: key = kv0+16t+4g+r, q = qb[qt]+c)
    if (nm0) {
      int q = qb[0] + c;
#pragma unroll
      for (int t = 0; t < 4; ++t)
#pragma unroll
        for (int r = 0; r < 4; ++r)
          if (kv0 + 16 * t + 4 * g + r > q) sv[0][t][r] = -1e38f;
    }
    if (act1 && nm1) {
      int q = qb[1] + c;
#pragma unroll
      for (int t = 0; t < 4; ++t)
#pragma unroll
        for (int r = 0; r < 4; ++r)
          if (kv0 + 16 * t + 4 * g + r > q) sv[1][t][r] = -1e38f;
    }

    softmax_store(0);
    if (act1) softmax_store(1);

    // ---- O^T += V^T . P^T (wave-private P, lgkmcnt ordering) ----
    short8 pbh[2][2], pbl[2][2];
#pragma unroll
    for (int kk = 0; kk < 2; ++kk) {
      int off = c * 128 + swz(c, 4 * kk + g) * 16;
      pbh[0][kk] = *(const short8*)(pw + off);
      pbl[0][kk] = *(const short8*)(pw + 4096 + off);
    }
    if (act1) {
#pragma unroll
      for (int kk = 0; kk < 2; ++kk) {
        int qrow = 16 + c;
        int off = qrow * 128 + swz(qrow, 4 * kk + g) * 16;
        pbh[1][kk] = *(const short8*)(pw + off);
        pbl[1][kk] = *(const short8*)(pw + 4096 + off);
      }
    }
#pragma unroll
    for (int td = 0; td < 4; ++td) {
      int d = 16 * td + c;                             // A row = output dim
#pragma unroll
      for (int kk = 0; kk < 2; ++kk) {
        int off = d * 128 + swz(d, 4 * kk + g) * 16;
        short8 vh = *(const short8*)(smem + VHI + off);
        short8 vl = *(const short8*)(smem + VLO + off);
        acc[td][0] = MFMA(vh, pbh[0][kk], acc[td][0]);
        acc[td][0] = MFMA(vh, pbl[0][kk], acc[td][0]);
        acc[td][0] = MFMA(vl, pbh[0][kk], acc[td][0]);
        if (act1) {
          acc[td][1] = MFMA(vh, pbh[1][kk], acc[td][1]);
          acc[td][1] = MFMA(vh, pbl[1][kk], acc[td][1]);
          acc[td][1] = MFMA(vl, pbh[1][kk], acc[td][1]);
        }
      }
    }
  }

  // ---- epilogue ----
#pragma unroll
  for (int qt = 0; qt < 2; ++qt) {
    float l = lsum[qt];
    l += __shfl_xor(l, 16);
    l += __shfl_xor(l, 32);
    float inv = 1.f / l;
    float* Ob = Og + base + (size_t)(qb[qt] + c) * DK_LEN;
#pragma unroll
    for (int td = 0; td < 4; ++td) {
      f32x4 o = acc[td][qt] * inv;
      *(f32x4*)(Ob + 16 * td + 4 * g) = o;
    }
  }
}

extern "C" void kernel_launch(void* const* d_in, const int* in_sizes, int n_in,
                              void* d_out, int out_size, void* d_ws, size_t ws_size,
                              hipStream_t stream) {
  (void)in_sizes; (void)n_in; (void)out_size;
  const float* Q = (const float*)d_in[0];
  const float* K = (const float*)d_in[1];
  const float* V = (const float*)d_in[2];
  float* O = (float*)d_out;
  dim3 grid(16, 32);   // x: chunk-pair index j, y: b*h
  const size_t WS_NEED = (size_t)32 * 32 * TILE_IMG;  // 32 MB
  if (ws_size >= WS_NEED) {
    prep_kv<<<dim3(32, 32), 256, 0, stream>>>(K, V, (char*)d_ws);
    fattn_fwd<true><<<grid, dim3(256), 0, stream>>>(Q, K, V, O, (const char*)d_ws);
  } else {
    fattn_fwd<false><<<grid, dim3(256), 0, stream>>>(Q, K, V, O, (const char*)d_ws);
  }
}